// Round 10
// baseline (60.353 us; speedup 1.0000x reference)
//
#include <hip/hip_runtime.h>

#define WAVE 64
#define WPB 2    // waves per block (128-thread blocks)
#define SPW 4    // consecutive segments per wave (software-pipelined)

// idx may be int32 (JAX default) or int64 (x64 enabled). Detection: odd 32-bit
// words in the upper half are high words of values < 2^31 under int64 layout
// (all zero); under int32 layout they are sorted values ~S/2 (nonzero).
__global__ void detect_idx64(const unsigned int* __restrict__ w32, long long N,
                             int* __restrict__ flag) {
    long long base = (N / 2) | 1LL;
    long long stride = ((N / 2) / 64) & ~1LL;
    if (stride < 2) stride = 2;
    long long p = base + (long long)threadIdx.x * stride;
    unsigned int v = (p < N) ? w32[p] : 0u;
    unsigned long long nz = __ballot(v != 0u);
    if (threadIdx.x == 0) *flag = (nz == 0ULL) ? 1 : 0;   // 1 -> int64
}

__device__ __forceinline__ int load_idx(const void* __restrict__ p,
                                        long long i, int is64) {
    return is64 ? (int)((const long long*)p)[i] : ((const int*)p)[i];
}

// One independent binary search per boundary: start[t] = lower_bound(idx, t).
// 64 independent 23-probe chains per wave; top tree levels are L2/L3-hot.
__global__ void find_bounds_bs(const void* __restrict__ idxp,
                               const int* __restrict__ flag,
                               int* __restrict__ start,
                               long long N, int S) {
    const int t = blockIdx.x * blockDim.x + threadIdx.x;
    if (t > S) return;
    const int is64 = *flag;
    long long lo = 0, hi = N;
    while (lo < hi) {
        long long mid = (lo + hi) >> 1;
        if (load_idx(idxp, mid, is64) < t) lo = mid + 1; else hi = mid;
    }
    start[t] = (int)lo;
}

// One wave : FOUR consecutive segments, software-pipelined. All 5 boundaries
// come from one coalesced load + shfl broadcast. Segment i+1's A-set loads
// issue before segment i's reduce/store phase (ping-pong register sets, fully
// static unroll), so its HBM latency hides under ~700 cy of compute. Same
// registers feed normalize+store (single pass over memory).
__global__ __launch_bounds__(WPB * WAVE)
void seg_norm(const float* __restrict__ pos,
              const float* __restrict__ w,
              const int* __restrict__ start,
              float* __restrict__ out,
              float* __restrict__ diam_out,
              int S) {
    const int wid  = threadIdx.x >> 6;
    const int lane = threadIdx.x & 63;
    const int s0 = (blockIdx.x * WPB + wid) * SPW;
    if (s0 >= S) return;

    // ---- all SPW+1 boundaries in one coalesced load ----
    int k = s0 + (lane < SPW ? lane : SPW);
    if (k > S) k = S;
    const int bv = start[k];
    const int e0 = __shfl(bv, 0), e1 = __shfl(bv, 1), e2 = __shfl(bv, 2),
              e3 = __shfl(bv, 3), e4 = __shfl(bv, 4);

    const float4* __restrict__ pos4 = (const float4*)pos;
    const float4* __restrict__ w4   = (const float4*)w;
    float4* __restrict__ out4 = (float4*)out;

    float4 PA_0 = {0,0,0,0}, PA_1 = {0,0,0,0}, PA_2 = {0,0,0,0}, PA_w = {0,0,0,0};
    float4 PB_0 = {0,0,0,0}, PB_1 = {0,0,0,0}, PB_2 = {0,0,0,0}, PB_w = {0,0,0,0};
    float4 BB_0 = {0,0,0,0}, BB_1 = {0,0,0,0}, BB_2 = {0,0,0,0}, BB_w = {0,0,0,0};

    // ---- initial prefetch: segment 0's A-set ----
    {
        const int ng0 = e0 >> 2, ng1 = (e1 + 3) >> 2;
        const int nga = ng0 + lane;
        if (nga < ng1) {
            PA_0 = pos4[3LL * nga]; PA_1 = pos4[3LL * nga + 1];
            PA_2 = pos4[3LL * nga + 2]; PA_w = w4[nga];
        }
    }

    // p+0: (r0.x,r0.y,r0.z) w.x | p+1: (r0.w,r1.x,r1.y) w.y
    // p+2: (r1.z,r1.w,r2.x) w.z | p+3: (r2.y,r2.z,r2.w) w.w
    #define PROC(PI, LO, HI, X, Y, Z, WV)                                \
    {                                                                    \
        bool in = ((PI) >= (LO)) & ((PI) < (HI));                        \
        float xv = (X), yv = (Y), zv = (Z);                              \
        float wv = in ? (WV) : 0.f;                                      \
        mnx = fminf(mnx, in ? xv :  INFINITY);                           \
        mxx = fmaxf(mxx, in ? xv : -INFINITY);                           \
        mny = fminf(mny, in ? yv :  INFINITY);                           \
        mxy = fmaxf(mxy, in ? yv : -INFINITY);                           \
        mnz = fminf(mnz, in ? zv :  INFINITY);                           \
        mxz = fmaxf(mxz, in ? zv : -INFINITY);                           \
        sw += wv;                                                        \
        swx = fmaf(wv, xv, swx);                                         \
        swy = fmaf(wv, yv, swy);                                         \
        swz = fmaf(wv, zv, swz);                                         \
    }
    #define PROC_GROUP(G, LO, HI, R0, R1, R2, RW)                        \
    {                                                                    \
        const int p_ = (G) << 2;                                         \
        PROC(p_ + 0, LO, HI, R0.x, R0.y, R0.z, RW.x)                     \
        PROC(p_ + 1, LO, HI, R0.w, R1.x, R1.y, RW.y)                     \
        PROC(p_ + 2, LO, HI, R1.z, R1.w, R2.x, RW.z)                     \
        PROC(p_ + 3, LO, HI, R2.y, R2.z, R2.w, RW.w)                     \
    }
    #define STORE_GROUP(G, LO, HI, R0, R1, R2)                               \
    {                                                                        \
        const int p_ = (G) << 2;                                             \
        float4 ra, rb, rc;                                                   \
        ra.x = (R0.x - cx) * inv; ra.y = (R0.y - cy) * inv;                  \
        ra.z = (R0.z - cz) * inv; ra.w = (R0.w - cx) * inv;                  \
        rb.x = (R1.x - cy) * inv; rb.y = (R1.y - cz) * inv;                  \
        rb.z = (R1.z - cx) * inv; rb.w = (R1.w - cy) * inv;                  \
        rc.x = (R2.x - cz) * inv; rc.y = (R2.y - cx) * inv;                  \
        rc.z = (R2.z - cy) * inv; rc.w = (R2.w - cz) * inv;                  \
        if (p_ >= (LO) && p_ + 4 <= (HI)) {                                  \
            out4[3LL * (G)] = ra; out4[3LL * (G) + 1] = rb;                  \
            out4[3LL * (G) + 2] = rc;                                        \
        } else {                                                             \
            const long long f = 12LL * (G);                                  \
            if (p_ + 0 >= (LO) && p_ + 0 < (HI)) {                           \
                out[f + 0] = ra.x; out[f + 1]  = ra.y; out[f + 2]  = ra.z;   \
            }                                                                \
            if (p_ + 1 >= (LO) && p_ + 1 < (HI)) {                           \
                out[f + 3] = ra.w; out[f + 4]  = rb.x; out[f + 5]  = rb.y;   \
            }                                                                \
            if (p_ + 2 >= (LO) && p_ + 2 < (HI)) {                           \
                out[f + 6] = rb.z; out[f + 7]  = rb.w; out[f + 8]  = rc.x;   \
            }                                                                \
            if (p_ + 3 >= (LO) && p_ + 3 < (HI)) {                           \
                out[f + 9] = rc.y; out[f + 10] = rc.z; out[f + 11] = rc.w;   \
            }                                                                \
        }                                                                    \
    }

    // One pipelined segment: consume CUR (prefetched), issue B-loads for this
    // segment and (if PF) next segment's A-loads into NXT, then reduce, then
    // normalize+store from registers. Tail loops cover >512-pt segments.
    #define SEG_ITER(SIDX, CUR, NXT, LO, HI, NLO, NHI, PF)                   \
    {                                                                        \
        const int g0 = (LO) >> 2, g1 = ((HI) + 3) >> 2;                      \
        const int ga = g0 + lane, gb = ga + WAVE;                            \
        const bool vb = gb < g1;                                             \
        const bool anyb = __any(vb);                                         \
        if (vb) {                                                            \
            BB_0 = pos4[3LL * gb]; BB_1 = pos4[3LL * gb + 1];                \
            BB_2 = pos4[3LL * gb + 2]; BB_w = w4[gb];                        \
        }                                                                    \
        if (PF) {                                                            \
            const int ng0 = (NLO) >> 2, ng1 = ((NHI) + 3) >> 2;              \
            const int nga = ng0 + lane;                                      \
            if (nga < ng1) {                                                 \
                NXT##0 = pos4[3LL * nga]; NXT##1 = pos4[3LL * nga + 1];      \
                NXT##2 = pos4[3LL * nga + 2]; NXT##w = w4[nga];              \
            }                                                                \
        }                                                                    \
        float mnx = INFINITY,  mny = INFINITY,  mnz = INFINITY;              \
        float mxx = -INFINITY, mxy = -INFINITY, mxz = -INFINITY;             \
        float sw = 0.f, swx = 0.f, swy = 0.f, swz = 0.f;                     \
        PROC_GROUP(ga, LO, HI, CUR##0, CUR##1, CUR##2, CUR##w)               \
        if (anyb) PROC_GROUP(gb, LO, HI, BB_0, BB_1, BB_2, BB_w)             \
        for (int g = g0 + 2 * WAVE + lane; g < g1; g += WAVE) {              \
            float4 c0 = pos4[3LL * g], c1 = pos4[3LL * g + 1],               \
                   c2 = pos4[3LL * g + 2];                                   \
            float4 cw = w4[g];                                               \
            PROC_GROUP(g, LO, HI, c0, c1, c2, cw)                            \
        }                                                                    \
        _Pragma("unroll")                                                    \
        for (int off = 1; off < WAVE; off <<= 1) {                           \
            mnx = fminf(mnx, __shfl_xor(mnx, off));                          \
            mny = fminf(mny, __shfl_xor(mny, off));                          \
            mnz = fminf(mnz, __shfl_xor(mnz, off));                          \
            mxx = fmaxf(mxx, __shfl_xor(mxx, off));                          \
            mxy = fmaxf(mxy, __shfl_xor(mxy, off));                          \
            mxz = fmaxf(mxz, __shfl_xor(mxz, off));                          \
            sw  += __shfl_xor(sw,  off);                                     \
            swx += __shfl_xor(swx, off);                                     \
            swy += __shfl_xor(swy, off);                                     \
            swz += __shfl_xor(swz, off);                                     \
        }                                                                    \
        const float diam = fmaxf(mxx - mnx, fmaxf(mxy - mny, mxz - mnz));    \
        const float wsafe = (sw == 0.f) ? 1.f : sw;                          \
        const float cx = swx / wsafe, cy = swy / wsafe, cz = swz / wsafe;    \
        const float inv = 1.f / (diam + 0.01f);                              \
        if (lane == 0 && (SIDX) < S) diam_out[SIDX] = diam;                  \
        STORE_GROUP(ga, LO, HI, CUR##0, CUR##1, CUR##2)                      \
        if (anyb) STORE_GROUP(gb, LO, HI, BB_0, BB_1, BB_2)                  \
        for (int g = g0 + 2 * WAVE + lane; g < g1; g += WAVE) {              \
            float4 c0 = pos4[3LL * g], c1 = pos4[3LL * g + 1],               \
                   c2 = pos4[3LL * g + 2];                                   \
            STORE_GROUP(g, LO, HI, c0, c1, c2)                               \
        }                                                                    \
    }

    SEG_ITER(s0 + 0, PA_, PB_, e0, e1, e1, e2, 1)
    SEG_ITER(s0 + 1, PB_, PA_, e1, e2, e2, e3, 1)
    SEG_ITER(s0 + 2, PA_, PB_, e2, e3, e3, e4, 1)
    SEG_ITER(s0 + 3, PB_, PA_, e3, e4, 0, 0, 0)

    #undef SEG_ITER
    #undef STORE_GROUP
    #undef PROC_GROUP
    #undef PROC
}

extern "C" void kernel_launch(void* const* d_in, const int* in_sizes, int n_in,
                              void* d_out, int out_size, void* d_ws, size_t ws_size,
                              hipStream_t stream) {
    const float* pos  = (const float*)d_in[0];
    const void*  idxp = d_in[1];
    const float* w    = (const float*)d_in[2];

    const long long N = (long long)in_sizes[0] / 3;     // 8388608
    const int S = out_size - in_sizes[0];               // 32768

    float* out = (float*)d_out;
    float* diam_out = out + (long long)in_sizes[0];     // tail of d_out

    int* flag  = (int*)d_ws;
    int* start = (int*)((char*)d_ws + 256);

    detect_idx64<<<1, 64, 0, stream>>>((const unsigned int*)idxp, N, flag);

    find_bounds_bs<<<(S + 1 + 63) / 64, 64, 0, stream>>>(idxp, flag, start, N, S);

    const int segs_per_block = WPB * SPW;               // 8
    seg_norm<<<(S + segs_per_block - 1) / segs_per_block, WPB * WAVE, 0, stream>>>(
        pos, w, start, out, diam_out, S);
}

// Round 12
// 57.102 us; speedup vs baseline: 1.0569x; 1.0569x over previous
//
#include <hip/hip_runtime.h>

#define WAVE 64
#define WPB 2    // waves per block (128-thread blocks)

// DPP-fused butterfly stage (VALU pipe, no LDS). ctrl must be a literal ->
// template parameter. All 64 lanes active at call sites.
template <int CTRL>
__device__ __forceinline__ float dpp_f(float x) {
    int xi = __builtin_bit_cast(int, x);
    int r  = __builtin_amdgcn_update_dpp(xi, xi, CTRL, 0xF, 0xF, false);
    return __builtin_bit_cast(float, r);
}
#define DPP_XOR1 0xB1   // quad_perm [1,0,3,2]
#define DPP_XOR2 0x4E   // quad_perm [2,3,0,1]
#define DPP_XOR4 0x141  // row_half_mirror (i ^ 7; == xor4 once xor1,2 done)
#define DPP_XOR8 0x140  // row_mirror      (i ^ 15; == xor8 once lower done)

// idx may be int32 (JAX default) or int64 (x64 enabled). Detection: odd 32-bit
// words in the upper half are high words of values < 2^31 under int64 layout
// (all zero); under int32 layout they are sorted values ~S/2 (nonzero).
__global__ void detect_idx64(const unsigned int* __restrict__ w32, long long N,
                             int* __restrict__ flag) {
    long long base = (N / 2) | 1LL;
    long long stride = ((N / 2) / 64) & ~1LL;
    if (stride < 2) stride = 2;
    long long p = base + (long long)threadIdx.x * stride;
    unsigned int v = (p < N) ? w32[p] : 0u;
    unsigned long long nz = __ballot(v != 0u);
    if (threadIdx.x == 0) *flag = (nz == 0ULL) ? 1 : 0;   // 1 -> int64
}

__device__ __forceinline__ int load_idx(const void* __restrict__ p,
                                        long long i, int is64) {
    return is64 ? (int)((const long long*)p)[i] : ((const int*)p)[i];
}

// One independent binary search per boundary: start[t] = lower_bound(idx, t).
// 64 independent 23-probe chains per wave; top tree levels are L2/L3-hot.
__global__ void find_bounds_bs(const void* __restrict__ idxp,
                               const int* __restrict__ flag,
                               int* __restrict__ start,
                               long long N, int S) {
    const int t = blockIdx.x * blockDim.x + threadIdx.x;
    if (t > S) return;
    const int is64 = *flag;
    long long lo = 0, hi = N;
    while (lo < hi) {
        long long mid = (lo + hi) >> 1;
        if (load_idx(idxp, mid, is64) < t) lo = mid + 1; else hi = mid;
    }
    start[t] = (int)lo;
}

// One wave per segment (R8 body; best measured). Both lane-iterations peeled
// statically so all 8 float4 loads issue before any dependent use; the SAME
// registers feed normalize+store. Butterfly: 4 DPP stages (VALU pipe) + 2
// shuffle stages (LDS pipe) — 20 LDS-pipe ops/segment instead of 60.
__global__ __launch_bounds__(WPB * WAVE)
void seg_norm(const float* __restrict__ pos,
              const float* __restrict__ w,
              const int* __restrict__ start,
              float* __restrict__ out,
              float* __restrict__ diam_out,
              int S) {
    const int s = blockIdx.x * WPB + (threadIdx.x >> 6);
    if (s >= S) return;
    const int lane = threadIdx.x & 63;

    const int lo = start[s], hi = start[s + 1];
    const int g0 = lo >> 2, g1 = (hi + 3) >> 2;       // 4-point groups

    const float4* __restrict__ pos4 = (const float4*)pos;
    const float4* __restrict__ w4   = (const float4*)w;

    const int ga = g0 + lane;          // iteration 0 group
    const int gb = ga + WAVE;          // iteration 1 group
    const bool va = ga < g1, vb = gb < g1;
    const bool anyb = __any(vb);       // ~45% of segments skip the B phase

    float4 a0 = {0,0,0,0}, a1 = {0,0,0,0}, a2 = {0,0,0,0}, aw = {0,0,0,0};
    float4 b0 = {0,0,0,0}, b1 = {0,0,0,0}, b2 = {0,0,0,0}, bw = {0,0,0,0};
    if (va) {
        a0 = pos4[3LL * ga]; a1 = pos4[3LL * ga + 1]; a2 = pos4[3LL * ga + 2];
        aw = w4[ga];
    }
    if (vb) {
        b0 = pos4[3LL * gb]; b1 = pos4[3LL * gb + 1]; b2 = pos4[3LL * gb + 2];
        bw = w4[gb];
    }

    float mnx = INFINITY,  mny = INFINITY,  mnz = INFINITY;
    float mxx = -INFINITY, mxy = -INFINITY, mxz = -INFINITY;
    float sw = 0.f, swx = 0.f, swy = 0.f, swz = 0.f;

    // p+0: (r0.x,r0.y,r0.z) w.x | p+1: (r0.w,r1.x,r1.y) w.y
    // p+2: (r1.z,r1.w,r2.x) w.z | p+3: (r2.y,r2.z,r2.w) w.w
    #define PROC(PI, X, Y, Z, WV)                                        \
    {                                                                    \
        bool in = ((PI) >= lo) & ((PI) < hi);                            \
        float xv = (X), yv = (Y), zv = (Z);                              \
        float wv = in ? (WV) : 0.f;                                      \
        mnx = fminf(mnx, in ? xv :  INFINITY);                           \
        mxx = fmaxf(mxx, in ? xv : -INFINITY);                           \
        mny = fminf(mny, in ? yv :  INFINITY);                           \
        mxy = fmaxf(mxy, in ? yv : -INFINITY);                           \
        mnz = fminf(mnz, in ? zv :  INFINITY);                           \
        mxz = fmaxf(mxz, in ? zv : -INFINITY);                           \
        sw += wv;                                                        \
        swx = fmaf(wv, xv, swx);                                         \
        swy = fmaf(wv, yv, swy);                                         \
        swz = fmaf(wv, zv, swz);                                         \
    }
    #define PROC_GROUP(G, R0, R1, R2, RW)                                \
    {                                                                    \
        const int p = (G) << 2;                                          \
        PROC(p + 0, R0.x, R0.y, R0.z, RW.x)                              \
        PROC(p + 1, R0.w, R1.x, R1.y, RW.y)                              \
        PROC(p + 2, R1.z, R1.w, R2.x, RW.z)                              \
        PROC(p + 3, R2.y, R2.z, R2.w, RW.w)                              \
    }

    PROC_GROUP(ga, a0, a1, a2, aw)
    if (anyb) PROC_GROUP(gb, b0, b1, b2, bw)

    // Pathological tail (segment > 512 points): never taken for this data.
    for (int g = g0 + 2 * WAVE + lane; g < g1; g += WAVE) {
        float4 c0 = pos4[3LL * g], c1 = pos4[3LL * g + 1], c2 = pos4[3LL * g + 2];
        float4 cw = w4[g];
        PROC_GROUP(g, c0, c1, c2, cw)
    }

    // ---- butterfly: xor1,2,4,8 on the VALU via DPP; xor16,32 via shuffle ----
    #define ALLV(STAGEOP)                                \
        mnx = fminf(mnx, STAGEOP(mnx));                  \
        mny = fminf(mny, STAGEOP(mny));                  \
        mnz = fminf(mnz, STAGEOP(mnz));                  \
        mxx = fmaxf(mxx, STAGEOP(mxx));                  \
        mxy = fmaxf(mxy, STAGEOP(mxy));                  \
        mxz = fmaxf(mxz, STAGEOP(mxz));                  \
        sw  += STAGEOP(sw);                              \
        swx += STAGEOP(swx);                             \
        swy += STAGEOP(swy);                             \
        swz += STAGEOP(swz);
    #define ST_X1(v)  dpp_f<DPP_XOR1>(v)
    #define ST_X2(v)  dpp_f<DPP_XOR2>(v)
    #define ST_X4(v)  dpp_f<DPP_XOR4>(v)
    #define ST_X8(v)  dpp_f<DPP_XOR8>(v)
    #define ST_X16(v) __shfl_xor((v), 16)
    #define ST_X32(v) __shfl_xor((v), 32)
    ALLV(ST_X1)
    ALLV(ST_X2)
    ALLV(ST_X4)
    ALLV(ST_X8)
    ALLV(ST_X16)
    ALLV(ST_X32)
    #undef ST_X1
    #undef ST_X2
    #undef ST_X4
    #undef ST_X8
    #undef ST_X16
    #undef ST_X32
    #undef ALLV

    const float diam = fmaxf(mxx - mnx, fmaxf(mxy - mny, mxz - mnz));
    const float wsafe = (sw == 0.f) ? 1.f : sw;
    const float cx = swx / wsafe, cy = swy / wsafe, cz = swz / wsafe;
    const float inv = 1.f / (diam + 0.01f);
    if (lane == 0) diam_out[s] = diam;

    float4* __restrict__ out4 = (float4*)out;

    #define STORE_GROUP(G, R0, R1, R2)                                       \
    {                                                                        \
        const int p = (G) << 2;                                              \
        float4 ra, rb, rc;                                                   \
        ra.x = (R0.x - cx) * inv; ra.y = (R0.y - cy) * inv;                  \
        ra.z = (R0.z - cz) * inv; ra.w = (R0.w - cx) * inv;                  \
        rb.x = (R1.x - cy) * inv; rb.y = (R1.y - cz) * inv;                  \
        rb.z = (R1.z - cx) * inv; rb.w = (R1.w - cy) * inv;                  \
        rc.x = (R2.x - cz) * inv; rc.y = (R2.y - cx) * inv;                  \
        rc.z = (R2.z - cy) * inv; rc.w = (R2.w - cz) * inv;                  \
        if (p >= lo && p + 4 <= hi) {                                        \
            out4[3LL * (G)] = ra; out4[3LL * (G) + 1] = rb;                  \
            out4[3LL * (G) + 2] = rc;                                        \
        } else {                                                             \
            const long long f = 12LL * (G);                                  \
            if (p + 0 >= lo && p + 0 < hi) {                                 \
                out[f + 0] = ra.x; out[f + 1]  = ra.y; out[f + 2]  = ra.z;   \
            }                                                                \
            if (p + 1 >= lo && p + 1 < hi) {                                 \
                out[f + 3] = ra.w; out[f + 4]  = rb.x; out[f + 5]  = rb.y;   \
            }                                                                \
            if (p + 2 >= lo && p + 2 < hi) {                                 \
                out[f + 6] = rb.z; out[f + 7]  = rb.w; out[f + 8]  = rc.x;   \
            }                                                                \
            if (p + 3 >= lo && p + 3 < hi) {                                 \
                out[f + 9] = rc.y; out[f + 10] = rc.z; out[f + 11] = rc.w;   \
            }                                                                \
        }                                                                    \
    }

    STORE_GROUP(ga, a0, a1, a2)
    if (anyb) STORE_GROUP(gb, b0, b1, b2)

    // Tail normalize (reload path; never taken for this data).
    for (int g = g0 + 2 * WAVE + lane; g < g1; g += WAVE) {
        float4 c0 = pos4[3LL * g], c1 = pos4[3LL * g + 1], c2 = pos4[3LL * g + 2];
        STORE_GROUP(g, c0, c1, c2)
    }

    #undef STORE_GROUP
    #undef PROC_GROUP
    #undef PROC
}

extern "C" void kernel_launch(void* const* d_in, const int* in_sizes, int n_in,
                              void* d_out, int out_size, void* d_ws, size_t ws_size,
                              hipStream_t stream) {
    const float* pos  = (const float*)d_in[0];
    const void*  idxp = d_in[1];
    const float* w    = (const float*)d_in[2];

    const long long N = (long long)in_sizes[0] / 3;     // 8388608
    const int S = out_size - in_sizes[0];               // 32768

    float* out = (float*)d_out;
    float* diam_out = out + (long long)in_sizes[0];     // tail of d_out

    int* flag  = (int*)d_ws;
    int* start = (int*)((char*)d_ws + 256);

    detect_idx64<<<1, 64, 0, stream>>>((const unsigned int*)idxp, N, flag);

    find_bounds_bs<<<(S + 1 + 63) / 64, 64, 0, stream>>>(idxp, flag, start, N, S);

    seg_norm<<<(S + WPB - 1) / WPB, WPB * WAVE, 0, stream>>>(
        pos, w, start, out, diam_out, S);
}